// Round 1
// baseline (150.375 us; speedup 1.0000x reference)
//
#include <hip/hip_runtime.h>

// EquivariantProductBasisBlock (MACE symmetric contraction), fp32.
// B=2048, C=128, S=10, DIN=9, DOUTS=(1,3,5), PATHS=(1,3,8).
// Strategy: per (species e, channel c) fold W into U -> dense table
// A3[m,i,j,k] (+A2[m,i,j], A1[m,i]) in LDS; per-(b,c) walk is fully
// static-indexed FMA chains with broadcast ds_read_b128.
//
// mm slot -> (l, m): 0 -> (0,0); 1..3 -> (1, mm-1); 4..8 -> (2, mm-4)

#define NB 2048
#define NC 128
#define NS 10
#define ND 9      // DIN
#define NMM 9     // total m slots over l

// ---------------- prep: deterministic counting sort of b by species ----------
__global__ __launch_bounds__(256) void prep_kernel(const float* __restrict__ attrs,
                                                   int* __restrict__ cnt,
                                                   int* __restrict__ start,
                                                   int* __restrict__ list)
{
    __shared__ int lcnt[256][NS];
    __shared__ int pre[256][NS];
    __shared__ int s_cnt[NS];
    __shared__ int s_start[NS];
    const int t = threadIdx.x;
    #pragma unroll
    for (int e = 0; e < NS; e++) lcnt[t][e] = 0;
    int myspec[8];
    #pragma unroll
    for (int r = 0; r < 8; r++) {
        int b = t * 8 + r;
        const float* row = attrs + b * NS;
        int e = 0;
        #pragma unroll
        for (int s = 1; s < NS; s++) e = (row[s] > 0.5f) ? s : e;
        myspec[r] = e;
        lcnt[t][e] += 1;
    }
    __syncthreads();
    if (t < NS) {
        int run = 0;
        for (int tt = 0; tt < 256; tt++) { pre[tt][t] = run; run += lcnt[tt][t]; }
        s_cnt[t] = run;
        cnt[t] = run;
    }
    __syncthreads();
    if (t == 0) {
        int run = 0;
        for (int e = 0; e < NS; e++) { s_start[e] = run; start[e] = run; run += s_cnt[e]; }
    }
    #pragma unroll
    for (int e = 0; e < NS; e++) lcnt[t][e] = 0;   // reuse as running counters
    __syncthreads();
    #pragma unroll
    for (int r = 0; r < 8; r++) {
        int b = t * 8 + r;
        int e = myspec[r];
        int pos = s_start[e] + pre[t][e] + lcnt[t][e];
        lcnt[t][e] += 1;
        list[pos] = b;
    }
}

// ---------------- main: per-(e,c) table build + per-(b,c) contraction --------
__global__ __launch_bounds__(256) void main_kernel(
    const float* __restrict__ x_in,
    const float* __restrict__ U1, const float* __restrict__ U2, const float* __restrict__ U3,
    const float* __restrict__ W1, const float* __restrict__ W2, const float* __restrict__ W3,
    const int* __restrict__ cnt, const int* __restrict__ start, const int* __restrict__ list,
    float* __restrict__ inter)
{
    const int c  = blockIdx.x;
    const int e  = blockIdx.y;
    const int ch = blockIdx.z;
    const int count = cnt[e];
    if (ch * 256 >= count) return;   // uniform early-exit (before any barrier)

    // row layout: 12 floats = A3[k=0..8], A2, A1(j==0 else 0), pad
    __shared__ float tab[NMM * 81 * 12];        // 34992 B
    __shared__ float w3s[3][8];
    __shared__ float w2s[3][3];
    __shared__ float w1s[3];

    const int t = threadIdx.x;
    if (t < 24)      { int l = t / 8, p = t % 8; w3s[l][p] = W3[((l * NS + e) * 8 + p) * NC + c]; }
    else if (t < 33) { int q = t - 24; int l = q / 3, p = q % 3; w2s[l][p] = W2[((l * NS + e) * 3 + p) * NC + c]; }
    else if (t < 36) { int l = t - 33; w1s[l] = W1[(l * NS + e) * NC + c]; }
    __syncthreads();

    // build table
    for (int r = t; r < NMM * 81; r += 256) {
        const int mm = r / 81;
        const int ij = r % 81;
        const int i = ij / 9, j = ij % 9;
        int l, m;
        if (mm == 0)     { l = 0; m = 0; }
        else if (mm < 4) { l = 1; m = mm - 1; }
        else             { l = 2; m = mm - 4; }
        const int lm = l * 5 + m;
        const float* u3p = U3 + (size_t)(lm * 729 + i * 81 + j * 9) * 8;  // [k*8+p]
        float* row = tab + r * 12;
        #pragma unroll
        for (int k = 0; k < ND; k++) {
            float s = 0.f;
            #pragma unroll
            for (int p = 0; p < 8; p++) s = fmaf(u3p[k * 8 + p], w3s[l][p], s);
            row[k] = s;
        }
        const float* u2p = U2 + (size_t)(lm * 81 + i * 9 + j) * 3;
        row[9]  = fmaf(u2p[0], w2s[l][0], fmaf(u2p[1], w2s[l][1], u2p[2] * w2s[l][2]));
        row[10] = (j == 0) ? U1[lm * 9 + i] * w1s[l] : 0.f;
        row[11] = 0.f;
    }
    __syncthreads();

    const int idx = ch * 256 + t;
    const bool active = idx < count;
    const int b = list[start[e] + (active ? idx : 0)];

    float x[ND];
    const float* xp = x_in + (size_t)(b * NC + c) * ND;
    #pragma unroll
    for (int k = 0; k < ND; k++) x[k] = xp[k];

    float* op = inter + (size_t)(b * NC + c) * 12;

    for (int mm = 0; mm < NMM; mm++) {
        const float* tb = tab + mm * 81 * 12;
        float acc = 0.f;
        #pragma unroll
        for (int i = 0; i < 9; i++) {
            float acc_i = 0.f;
            #pragma unroll
            for (int j = 0; j < 9; j++) {
                const float4* rq = (const float4*)(tb + (i * 9 + j) * 12);
                float4 r0 = rq[0];
                float4 r1 = rq[1];
                float4 r2 = rq[2];   // x=A3[8], y=A2, z=A1, w=pad
                float s0 = fmaf(x[0], r0.x, fmaf(x[1], r0.y, fmaf(x[2], r0.z, fmaf(x[3], r0.w, r2.y))));
                float s1 = fmaf(x[4], r1.x, fmaf(x[5], r1.y, fmaf(x[6], r1.z, fmaf(x[7], r1.w, x[8] * r2.x))));
                float c1 = s0 + s1;
                acc_i = fmaf(x[j], c1, acc_i);
                if (j == 0) acc_i += r2.z;    // A1 term (compile-time branch)
            }
            acc = fmaf(x[i], acc_i, acc);
        }
        if (active) op[mm] = acc;
    }
}

// ---------------- final: y[b,dd,m] = sum_c inter[b,c,mm]*Wlin[l,c,dd]/sqrt(C) + sc
__global__ __launch_bounds__(256) void final_kernel(
    const float* __restrict__ inter, const float* __restrict__ Wlin,
    const float* __restrict__ sc, float* __restrict__ out)
{
    __shared__ float sInter[4 * NC * 12];   // 24 KB
    const int t = threadIdx.x;
    const int b0 = blockIdx.x * 4;
    const float4* src = (const float4*)(inter + (size_t)b0 * NC * 12);
    float4* dst = (float4*)sInter;
    #pragma unroll
    for (int q = 0; q < 6; q++) dst[t + q * 256] = src[t + q * 256];
    __syncthreads();

    const int dd = t & 127;
    const int bh = t >> 7;
    float acc[2][NMM];
    #pragma unroll
    for (int u = 0; u < 2; u++)
        #pragma unroll
        for (int mm = 0; mm < NMM; mm++) acc[u][mm] = 0.f;

    const float* wp = Wlin + dd;
    for (int cc = 0; cc < NC; cc++) {
        float wl0 = wp[(0 * NC + cc) * NC];
        float wl1 = wp[(1 * NC + cc) * NC];
        float wl2 = wp[(2 * NC + cc) * NC];
        #pragma unroll
        for (int u = 0; u < 2; u++) {
            const float* ip = sInter + ((bh + u * 2) * NC + cc) * 12;
            float4 i0 = *(const float4*)ip;
            float4 i1 = *(const float4*)(ip + 4);
            float  i8 = ip[8];
            acc[u][0] = fmaf(i0.x, wl0, acc[u][0]);
            acc[u][1] = fmaf(i0.y, wl1, acc[u][1]);
            acc[u][2] = fmaf(i0.z, wl1, acc[u][2]);
            acc[u][3] = fmaf(i0.w, wl1, acc[u][3]);
            acc[u][4] = fmaf(i1.x, wl2, acc[u][4]);
            acc[u][5] = fmaf(i1.y, wl2, acc[u][5]);
            acc[u][6] = fmaf(i1.z, wl2, acc[u][6]);
            acc[u][7] = fmaf(i1.w, wl2, acc[u][7]);
            acc[u][8] = fmaf(i8,   wl2, acc[u][8]);
        }
    }

    const float inv = 0.08838834764831845f;   // 1/sqrt(128)
    #pragma unroll
    for (int u = 0; u < 2; u++) {
        const int b = b0 + bh + u * 2;
        float* orow = out + (size_t)b * 1152;
        const float* scrow = sc + (size_t)b * 1152;
        orow[dd] = fmaf(acc[u][0], inv, scrow[dd]);
        #pragma unroll
        for (int m = 0; m < 3; m++)
            orow[128 + dd * 3 + m] = fmaf(acc[u][1 + m], inv, scrow[128 + dd * 3 + m]);
        #pragma unroll
        for (int m = 0; m < 5; m++)
            orow[512 + dd * 5 + m] = fmaf(acc[u][4 + m], inv, scrow[512 + dd * 5 + m]);
    }
}

extern "C" void kernel_launch(void* const* d_in, const int* in_sizes, int n_in,
                              void* d_out, int out_size, void* d_ws, size_t ws_size,
                              hipStream_t stream) {
    const float* node_feats = (const float*)d_in[0];
    const float* node_attrs = (const float*)d_in[1];
    const float* sc   = (const float*)d_in[2];
    const float* U1   = (const float*)d_in[3];
    const float* U2   = (const float*)d_in[4];
    const float* U3   = (const float*)d_in[5];
    const float* W1   = (const float*)d_in[6];
    const float* W2   = (const float*)d_in[7];
    const float* W3   = (const float*)d_in[8];
    const float* Wlin = (const float*)d_in[9];
    float* out = (float*)d_out;

    char* ws = (char*)d_ws;
    int* cnt   = (int*)(ws + 0);
    int* start = (int*)(ws + 64);
    int* list  = (int*)(ws + 128);
    float* inter = (float*)(ws + 16384);   // NB*NC*12 floats = 12.58 MB

    hipLaunchKernelGGL(prep_kernel, dim3(1), dim3(256), 0, stream,
                       node_attrs, cnt, start, list);
    hipLaunchKernelGGL(main_kernel, dim3(NC, NS, 3), dim3(256), 0, stream,
                       node_feats, U1, U2, U3, W1, W2, W3, cnt, start, list, inter);
    hipLaunchKernelGGL(final_kernel, dim3(NB / 4), dim3(256), 0, stream,
                       inter, Wlin, sc, out);
}